// Round 1
// baseline (71.124 us; speedup 1.0000x reference)
//
#include <hip/hip_runtime.h>

// GetCost: per-pixel inverse-depth resampling of depth-plane profiles.
// Inputs (setup_inputs order):
//   d_in[0] depth_values   (B,1,H,W) f32
//   d_in[1] pro0           (B*H*W, G=8, D=32) f32
//   d_in[2] pro1           (B*H*W, 1,   D=32) f32
//   d_in[3] depth_interval (B,1,H,W) f32
//   d_in[4] CostNum        (1,) int  -- derived on host from out_size instead
// Output: (B, (G+1)*ND, H, W) f32, sim channels first then corr.

static constexpr int   HW_  = 256 * 320;   // 81920
static constexpr int   DPL  = 32;          // depth planes
static constexpr float DMIN = 425.0f;
static constexpr float DMAX = 935.0f;

template <int ND, int GRP>
__global__ __launch_bounds__(256)
void getcost_kernel(const float* __restrict__ dv,
                    const float* __restrict__ pro0,
                    const float* __restrict__ pro1,
                    const float* __restrict__ di,
                    float* __restrict__ out,
                    int npix)
{
    int p = blockIdx.x * blockDim.x + threadIdx.x;
    if (p >= npix) return;
    int b  = p / HW_;
    int hw = p - b * HW_;

    const float inv_min = (float)(1.0 / (double)DMAX);
    const float inv_max = (float)(1.0 / (double)DMIN);
    const float denom   = (inv_max - inv_min) + 1e-10f;

    float cur = 1.0f / dv[p];
    float itv = di[p];
    const float ndf = (float)ND;
    float low     = cur - (ndf * 0.5f) * itv;
    float new_itv = (ndf * itv) / (ndf - 1.0f);

    // Per-sample indices/weights, fully unrolled -> registers (no scratch).
    int   i0c[ND], i1c[ND];
    float w0v[ND], w1v[ND];
    bool  v0v[ND], v1v[ND];

#pragma unroll
    for (int j = 0; j < ND; ++j) {
        float samp_inv = low + (float)j * new_itv;
        float dsamp    = 1.0f / samp_inv;            // reference: 1/samp_inv
        float x = (1.0f / dsamp - inv_min) / denom * (float)(DPL - 1);
        float x0 = floorf(x);
        float w1 = x - x0;
        float x1 = x0 + 1.0f;
        v0v[j] = (x0 >= 0.0f) && (x0 <= (float)(DPL - 1));
        v1v[j] = (x1 >= 0.0f) && (x1 <= (float)(DPL - 1));
        i0c[j] = (int)fminf(fmaxf(x0, 0.0f), (float)(DPL - 1));
        i1c[j] = (int)fminf(fmaxf(x1, 0.0f), (float)(DPL - 1));
        w1v[j] = w1;
        w0v[j] = 1.0f - w1;
    }

    const float* __restrict__ p1row = pro1 + (size_t)p * DPL;
    const float* __restrict__ p0pix = pro0 + (size_t)p * (GRP * DPL);
    float* __restrict__ outp = out + (size_t)b * ((GRP + 1) * ND) * HW_ + hw;

    // sim: channels [0, ND)
#pragma unroll
    for (int j = 0; j < ND; ++j) {
        float a = v0v[j] ? p1row[i0c[j]] : 0.0f;
        float c = v1v[j] ? p1row[i1c[j]] : 0.0f;
        outp[(size_t)j * HW_] = a * w0v[j] + c * w1v[j];
    }
    // corr: channels [ND + g*ND + j]
#pragma unroll
    for (int g = 0; g < GRP; ++g) {
        const float* __restrict__ row = p0pix + g * DPL;
#pragma unroll
        for (int j = 0; j < ND; ++j) {
            float a = v0v[j] ? row[i0c[j]] : 0.0f;
            float c = v1v[j] ? row[i1c[j]] : 0.0f;
            outp[(size_t)(ND + g * ND + j) * HW_] = a * w0v[j] + c * w1v[j];
        }
    }
}

// Generic fallback for unexpected ND / G (runtime loops, no per-thread arrays).
__global__ __launch_bounds__(256)
void getcost_generic(const float* __restrict__ dv,
                     const float* __restrict__ pro0,
                     const float* __restrict__ pro1,
                     const float* __restrict__ di,
                     float* __restrict__ out,
                     int npix, int nd, int grp)
{
    int p = blockIdx.x * blockDim.x + threadIdx.x;
    if (p >= npix) return;
    int b  = p / HW_;
    int hw = p - b * HW_;

    const float inv_min = (float)(1.0 / (double)DMAX);
    const float inv_max = (float)(1.0 / (double)DMIN);
    const float denom   = (inv_max - inv_min) + 1e-10f;

    float cur = 1.0f / dv[p];
    float itv = di[p];
    float ndf = (float)nd;
    float low     = cur - (ndf * 0.5f) * itv;
    float new_itv = (ndf * itv) / (ndf - 1.0f);

    const float* p1row = pro1 + (size_t)p * DPL;
    const float* p0pix = pro0 + (size_t)p * (size_t)grp * DPL;
    float* outp = out + (size_t)b * ((grp + 1) * nd) * HW_ + hw;

    for (int j = 0; j < nd; ++j) {
        float samp_inv = low + (float)j * new_itv;
        float dsamp    = 1.0f / samp_inv;
        float x = (1.0f / dsamp - inv_min) / denom * (float)(DPL - 1);
        float x0 = floorf(x);
        float w1 = x - x0;
        float x1 = x0 + 1.0f;
        bool v0 = (x0 >= 0.0f) && (x0 <= (float)(DPL - 1));
        bool v1 = (x1 >= 0.0f) && (x1 <= (float)(DPL - 1));
        int i0 = (int)fminf(fmaxf(x0, 0.0f), (float)(DPL - 1));
        int i1 = (int)fminf(fmaxf(x1, 0.0f), (float)(DPL - 1));
        float w0 = 1.0f - w1;

        float a = v0 ? p1row[i0] : 0.0f;
        float c = v1 ? p1row[i1] : 0.0f;
        outp[(size_t)j * HW_] = a * w0 + c * w1;
        for (int g = 0; g < grp; ++g) {
            const float* row = p0pix + (size_t)g * DPL;
            float aa = v0 ? row[i0] : 0.0f;
            float cc = v1 ? row[i1] : 0.0f;
            outp[(size_t)(nd + g * nd + j) * HW_] = aa * w0 + cc * w1;
        }
    }
}

extern "C" void kernel_launch(void* const* d_in, const int* in_sizes, int n_in,
                              void* d_out, int out_size, void* d_ws, size_t ws_size,
                              hipStream_t stream) {
    const float* dv   = (const float*)d_in[0];
    const float* pro0 = (const float*)d_in[1];
    const float* pro1 = (const float*)d_in[2];
    const float* di   = (const float*)d_in[3];
    float* out = (float*)d_out;

    int npix = in_sizes[0];                        // B*1*H*W
    int grp  = in_sizes[1] / (npix * DPL);         // pro0 groups (8)
    int nd   = out_size / (npix * (grp + 1));      // CostNum (4), derived on host

    int threads = 256;
    int blocks  = (npix + threads - 1) / threads;

    if (nd == 4 && grp == 8) {
        getcost_kernel<4, 8><<<blocks, threads, 0, stream>>>(dv, pro0, pro1, di, out, npix);
    } else {
        getcost_generic<<<blocks, threads, 0, stream>>>(dv, pro0, pro1, di, out, npix, nd, grp);
    }
}